// Round 4
// baseline (101.446 us; speedup 1.0000x reference)
//
#include <hip/hip_runtime.h>
#include <math.h>

// Problem constants (match reference setup_inputs)
#define B 32
#define S 4096
#define E 256
#define H 256
#define T 64
#define J (T - 2)
#define NSEG (B * T)  // 2048 segments, one block each

__device__ __forceinline__ float dot4(float4 v, float4 w) {
    return fmaf(v.x, w.x, fmaf(v.y, w.y, fmaf(v.z, w.z, v.w * w.w)));
}

// Single fused kernel.
// Phase 1 (all 2048 blocks): t[g] = mean over segment rows of dot(enc_row, We).
//   Per-thread scalar accumulator: sum over rows x features commutes, so the
//   block reduce at the end handles both. Hot loop = pure coalesced float4
//   stream + 4 independent FMA chains. No shuffles in the loop.
// Phase 2 (block 0 only, after atomic-counter barrier): per-b suffix-LSE scan
//   (62 serial combines per b, one thread per b), then mean -> out[0].
__global__ __launch_bounds__(256) void fused_kernel(
    const float* __restrict__ enc,
    const int* __restrict__ ends,
    const float* __restrict__ We,
    float* __restrict__ t,
    unsigned int* __restrict__ counter,
    float* __restrict__ out) {
    const int g    = blockIdx.x;       // segment id = b*T + tau
    const int tid  = threadIdx.x;
    const int w    = tid >> 6;
    const int lane = tid & 63;
    const int tau  = g & (T - 1);
    const int b    = g >> 6;

    __shared__ float red[256];
    __shared__ float tl[NSEG];
    __shared__ float pl[B];

    const int e  = ends[g];
    const int st = (tau == 0) ? 0 : (ends[g - 1] + 1);

    const float4  wv   = reinterpret_cast<const float4*>(We)[lane];
    const float4* base = reinterpret_cast<const float4*>(enc) + (size_t)b * S * 64;

    // Rows st..e, round-robin over 4 waves, unroll-4 per wave (4 load streams).
    float s0 = 0.f, s1 = 0.f, s2 = 0.f, s3 = 0.f;
    int r = st + w;
    for (; r + 12 <= e; r += 16) {
        float4 v0 = base[(size_t)r * 64 + lane];
        float4 v1 = base[(size_t)(r + 4) * 64 + lane];
        float4 v2 = base[(size_t)(r + 8) * 64 + lane];
        float4 v3 = base[(size_t)(r + 12) * 64 + lane];
        s0 += dot4(v0, wv);
        s1 += dot4(v1, wv);
        s2 += dot4(v2, wv);
        s3 += dot4(v3, wv);
    }
    for (; r <= e; r += 4) s0 += dot4(base[(size_t)r * 64 + lane], wv);

    red[tid] = (s0 + s1) + (s2 + s3);
    __syncthreads();

    if (w == 0) {
        float p = red[lane] + red[64 + lane] + red[128 + lane] + red[192 + lane];
#pragma unroll
        for (int off = 32; off >= 1; off >>= 1) p += __shfl_xor(p, off, 64);
        if (lane == 0) {
            t[g] = p / (float)(e - st + 1);
            __threadfence();          // release: t[g] visible before counter inc
            atomicAdd(counter, 1u);   // device-scope
        }
    }

    if (g != 0) return;

    // ---- Block 0: wait for all segments (it is dispatched first, so it is
    // resident; no other block ever waits -> no deadlock). ----
    if (tid == 0) {
        while (__hip_atomic_load(counter, __ATOMIC_ACQUIRE,
                                 __HIP_MEMORY_SCOPE_AGENT) < NSEG)
            __builtin_amdgcn_s_sleep(8);
    }
    __syncthreads();
    __threadfence();  // acquire side: no stale t reads

    for (int i = tid; i < NSEG; i += 256) tl[i] = t[i];
    __syncthreads();

    if (tid < B) {
        const float* tb = tl + tid * T;
        // Suffix LSE scan: state (M, a) = logsumexp over tb[j+2 .. T-1].
        float M = tb[T - 1], a = 1.0f, ls = 0.0f;
        for (int j = J - 1; j >= 0; --j) {
            ls += logf(a) + M - tb[j + 2];
            if (j > 0) {
                float x  = tb[j + 1];
                float M2 = fmaxf(M, x);
                a = a * __expf(M - M2) + __expf(x - M2);
                M = M2;
            }
        }
        pl[tid] = ls;
    }
    __syncthreads();
    if (tid == 0) {
        float tot = 0.f;
        for (int i = 0; i < B; ++i) tot += pl[i];
        out[0] = tot / (float)(B * J);
    }
}

extern "C" void kernel_launch(void* const* d_in, const int* in_sizes, int n_in,
                              void* d_out, int out_size, void* d_ws, size_t ws_size,
                              hipStream_t stream) {
    // Inputs: 0 encoder_output (B,S,E) f32; 1 his_turn_end_ids (B,T) i32;
    // 2..5 LSTM weights (algebraically dead); 6 fc_w (1,H+E); 7 fc_b (dead).
    // loss[b,j] = LSE_{m=j+2..T-1}(t[b,m]) - t[b,j+2], t = seg_mean(enc) @ We,
    // We = fc_w[0, H:]. LSTM path and fc_b cancel inside LSE - logits[...,0].
    const float* enc  = (const float*)d_in[0];
    const int*   ends = (const int*)d_in[1];
    const float* We   = (const float*)d_in[6] + H;

    float*        t       = (float*)d_ws;                    // NSEG floats
    unsigned int* counter = (unsigned int*)((float*)d_ws + NSEG);
    float*        out     = (float*)d_out;

    hipMemsetAsync(counter, 0, sizeof(unsigned int), stream);
    fused_kernel<<<NSEG, 256, 0, stream>>>(enc, ends, We, t, counter, out);
}